// Round 1
// baseline (613.916 us; speedup 1.0000x reference)
//
#include <hip/hip_runtime.h>
#include <hip/hip_bf16.h>

#define S_LEN 1536
#define BATCH 2
#define DMODEL 1024
#define NHEAD 16
#define DHEAD 64
#define FDIM 384          // 2*DHEAD*N_ROLL
#define CHUNK 64
#define NCHUNK 24         // S_LEN / CHUNK
#define ROWS (S_LEN*BATCH)
#define SCALE_F 0.125f
#define EPS_D 1e-5f
#define EPS_LN 1e-5f

typedef unsigned short u16;

static __device__ __forceinline__ float bf2f(u16 a) {
  return __uint_as_float(((unsigned)a) << 16);
}
static __device__ __forceinline__ u16 f2bf(float x) {
  unsigned u = __float_as_uint(x);
  unsigned r = (u + 0x7FFFu + ((u >> 16) & 1u)) >> 16;
  return (u16)r;
}

// C[M][N] = A[M][K] * W[N][K]^T   (all row-major, M%64==N%64==K%16==0)
__global__ __launch_bounds__(256) void gemm_nt_f32(
    const float* __restrict__ A, const float* __restrict__ W,
    float* __restrict__ C, int M, int N, int K) {
  __shared__ float As[16][68];
  __shared__ float Ws[16][68];
  const int t = threadIdx.x;
  const int tx = t & 15, ty = t >> 4;
  const int m0 = blockIdx.y * 64, n0 = blockIdx.x * 64;
  const int lr = t >> 2, lk = (t & 3) << 2;
  const float* Ap = A + (size_t)(m0 + lr) * K + lk;
  const float* Wp = W + (size_t)(n0 + lr) * K + lk;
  float acc[4][4] = {};
  for (int k0 = 0; k0 < K; k0 += 16) {
    float4 av = *(const float4*)(Ap + k0);
    float4 wv = *(const float4*)(Wp + k0);
    __syncthreads();
    As[lk + 0][lr] = av.x; As[lk + 1][lr] = av.y;
    As[lk + 2][lr] = av.z; As[lk + 3][lr] = av.w;
    Ws[lk + 0][lr] = wv.x; Ws[lk + 1][lr] = wv.y;
    Ws[lk + 2][lr] = wv.z; Ws[lk + 3][lr] = wv.w;
    __syncthreads();
#pragma unroll
    for (int kk = 0; kk < 16; ++kk) {
      float4 a4 = *(const float4*)&As[kk][ty << 2];
      float4 b4 = *(const float4*)&Ws[kk][tx << 2];
      float a[4] = {a4.x, a4.y, a4.z, a4.w};
      float bq[4] = {b4.x, b4.y, b4.z, b4.w};
#pragma unroll
      for (int r = 0; r < 4; ++r)
#pragma unroll
        for (int cc = 0; cc < 4; ++cc) acc[r][cc] += a[r] * bq[cc];
    }
  }
#pragma unroll
  for (int r = 0; r < 4; ++r) {
    float4 o = {acc[r][0], acc[r][1], acc[r][2], acc[r][3]};
    *(float4*)(C + (size_t)(m0 + (ty << 2) + r) * N + n0 + (tx << 2)) = o;
  }
}

// DPFP: x[64] -> y[128]=[relu(x),relu(-x)] -> feat[384]: y[j]*y[(j-i)&127], i=1..3
// feat layout: [B][NHEAD][S][FDIM] bf16. Optionally copies v out of kvproj.
__global__ __launch_bounds__(128) void dpfp_kernel(
    const float* __restrict__ proj, int ldp, int col0,
    u16* __restrict__ feat,
    const float* __restrict__ vsrc, float* __restrict__ vdst) {
  const int t = threadIdx.x;
  const int n = blockIdx.x, b = blockIdx.y, s = blockIdx.z;
  const int r = s * BATCH + b;
  __shared__ float y[128];
  float x = proj[(size_t)r * ldp + col0 + n * DHEAD + (t & 63)];
  y[t] = fmaxf(t < 64 ? x : -x, 0.0f);
  __syncthreads();
  u16* outp = feat + ((size_t)(b * NHEAD + n) * S_LEN + s) * FDIM;
  float yt = y[t];
#pragma unroll
  for (int i = 1; i <= 3; ++i)
    outp[(i - 1) * 128 + t] = f2bf(yt * y[(t - i) & 127]);
  if (vsrc && t < 64)
    vdst[((size_t)(b * NHEAD + n) * S_LEN + s) * DHEAD + t] =
        vsrc[(size_t)r * 2048 + 1024 + n * DHEAD + t];
}

// Per-chunk KV outer-product sums: KV_c[f][d] = sum_{j in chunk} kf[j][f]*v[j][d]
__global__ __launch_bounds__(256) void chunk_kv_kernel(
    const u16* __restrict__ kf, const float* __restrict__ vbuf,
    float* __restrict__ kvstate) {
  const int t = threadIdx.x;
  const int c = blockIdx.x, n = blockIdx.y, b = blockIdx.z;
  const int bn = b * NHEAD + n;
  const u16* kfp = kf + ((size_t)bn * S_LEN + c * CHUNK) * FDIM;
  const float* vp = vbuf + ((size_t)bn * S_LEN + c * CHUNK) * DHEAD;
  __shared__ float kfs[FDIM];
  __shared__ float vs[DHEAD];
  const int f0 = (t >> 4) * 24, d0 = (t & 15) << 2;
  float acc[24][4] = {};
  for (int j = 0; j < CHUNK; ++j) {
    __syncthreads();
    for (int e = t; e < FDIM; e += 256) kfs[e] = bf2f(kfp[(size_t)j * FDIM + e]);
    if (t < DHEAD) vs[t] = vp[(size_t)j * DHEAD + t];
    __syncthreads();
    float4 vv = *(const float4*)&vs[d0];
#pragma unroll
    for (int u = 0; u < 6; ++u) {
      float4 kq = *(const float4*)&kfs[f0 + u * 4];
      float kk[4] = {kq.x, kq.y, kq.z, kq.w};
#pragma unroll
      for (int q = 0; q < 4; ++q) {
        acc[u * 4 + q][0] += kk[q] * vv.x;
        acc[u * 4 + q][1] += kk[q] * vv.y;
        acc[u * 4 + q][2] += kk[q] * vv.z;
        acc[u * 4 + q][3] += kk[q] * vv.w;
      }
    }
  }
  float* outp = kvstate + ((size_t)bn * NCHUNK + c) * (FDIM * DHEAD);
#pragma unroll
  for (int ff = 0; ff < 24; ++ff) {
    float4 o = {acc[ff][0], acc[ff][1], acc[ff][2], acc[ff][3]};
    *(float4*)(outp + (size_t)(f0 + ff) * DHEAD + d0) = o;
  }
}

// Per-chunk feature sums: Ksum_c[f] = sum_{j in chunk} kf[j][f]
__global__ __launch_bounds__(384) void ksum_kernel(
    const u16* __restrict__ kf, float* __restrict__ ksumst) {
  const int f = threadIdx.x;
  const int c = blockIdx.x, n = blockIdx.y, b = blockIdx.z;
  const int bn = b * NHEAD + n;
  const u16* kfp = kf + ((size_t)bn * S_LEN + c * CHUNK) * FDIM + f;
  float acc = 0.f;
  for (int j = 0; j < CHUNK; ++j) acc += bf2f(kfp[(size_t)j * FDIM]);
  ksumst[((size_t)bn * NCHUNK + c) * FDIM + f] = acc;
}

// Exclusive prefix over chunks, elementwise, in place.
__global__ __launch_bounds__(256) void scan_kernel(
    float* __restrict__ kvstate, float* __restrict__ ksumst) {
  const int bid = blockIdx.x;
  if (bid < 3072) {
    int gid = bid * 256 + threadIdx.x;      // 32*24576 elements
    int bn = gid / 24576, e = gid % 24576;
    float* base = kvstate + (size_t)bn * NCHUNK * 24576 + e;
    float a = 0.f;
    for (int c = 0; c < NCHUNK; ++c) {
      float x = base[(size_t)c * 24576];
      base[(size_t)c * 24576] = a;
      a += x;
    }
  } else {
    int gid = (bid - 3072) * 256 + threadIdx.x;  // 32*384 elements
    int bn = gid / FDIM, f = gid % FDIM;
    float* base = ksumst + (size_t)bn * NCHUNK * FDIM + f;
    float a = 0.f;
    for (int c = 0; c < NCHUNK; ++c) {
      float x = base[(size_t)c * FDIM];
      base[(size_t)c * FDIM] = a;
      a += x;
    }
  }
}

// Fused per-chunk attention: inter (qf·KVprefix, qf·Ksumprefix) + intra
// (causal 64x64 scores) + normalization. Writes attnvec rows [s*B+b][n*64+d].
__global__ __launch_bounds__(256) void attn_kernel(
    const u16* __restrict__ qf, const u16* __restrict__ kf,
    const float* __restrict__ vbuf, const float* __restrict__ kvstate,
    const float* __restrict__ ksumst, float* __restrict__ attnvec) {
  const int t = threadIdx.x;
  const int c = blockIdx.x, n = blockIdx.y, b = blockIdx.z;
  const int bn = b * NHEAD + n;
  const int s0 = c * CHUNK;
  const u16* qfp = qf + ((size_t)bn * S_LEN + s0) * FDIM;
  const u16* kfp = kf + ((size_t)bn * S_LEN + s0) * FDIM;
  const float* vp = vbuf + ((size_t)bn * S_LEN + s0) * DHEAD;
  const float* kvp = kvstate + ((size_t)bn * NCHUNK + c) * (FDIM * DHEAD);
  const float* ksp = ksumst + ((size_t)bn * NCHUNK + c) * FDIM;

  __shared__ float Qs[16][68];
  __shared__ float Ks[16][68];       // also reused as KV-prefix slab
  __shared__ float St[CHUNK][68];    // transposed scores St[j][i]
  __shared__ float Vs[CHUNK][68];
  __shared__ float ks_l[FDIM];
  __shared__ float den_l[CHUNK];

  for (int e = t; e < FDIM; e += 256) ks_l[e] = ksp[e];
  for (int i = t; i < CHUNK * 16; i += 256) {
    int j = i >> 4, dq = (i & 15) << 2;
    *(float4*)&Vs[j][dq] = *(const float4*)(vp + (size_t)j * DHEAD + dq);
  }

  const int tx = t & 15, ty = t >> 4;
  const int i0 = ty << 2, d0 = tx << 2, j0 = tx << 2;
  const int lrow = t >> 2, lk = (t & 3) << 2;

  float acc[4][4] = {};
  float den = 0.f;

  // Phase B: inter part, num += Qf*KVprefix ; den += Qf*Ksumprefix
  for (int k0 = 0; k0 < FDIM; k0 += 16) {
    ushort4 qv = *(const ushort4*)(qfp + (size_t)lrow * FDIM + k0 + lk);
    float4 kvv = *(const float4*)(kvp + (size_t)(k0 + (t >> 4)) * DHEAD + ((t & 15) << 2));
    __syncthreads();
    Qs[lk + 0][lrow] = bf2f(qv.x);
    Qs[lk + 1][lrow] = bf2f(qv.y);
    Qs[lk + 2][lrow] = bf2f(qv.z);
    Qs[lk + 3][lrow] = bf2f(qv.w);
    *(float4*)&Ks[t >> 4][(t & 15) << 2] = kvv;
    __syncthreads();
#pragma unroll
    for (int kk = 0; kk < 16; ++kk) {
      float4 a4 = *(const float4*)&Qs[kk][i0];
      float4 b4 = *(const float4*)&Ks[kk][d0];
      float a[4] = {a4.x, a4.y, a4.z, a4.w};
      float bq[4] = {b4.x, b4.y, b4.z, b4.w};
#pragma unroll
      for (int r = 0; r < 4; ++r)
#pragma unroll
        for (int cc = 0; cc < 4; ++cc) acc[r][cc] += a[r] * bq[cc];
    }
    if (t < CHUNK) {
#pragma unroll
      for (int kk = 0; kk < 16; ++kk) den += Qs[kk][t] * ks_l[k0 + kk];
    }
  }

  // Phase C: intra scores (causal within chunk), stored transposed
  float sacc[4][4] = {};
  for (int k0 = 0; k0 < FDIM; k0 += 16) {
    ushort4 qv = *(const ushort4*)(qfp + (size_t)lrow * FDIM + k0 + lk);
    ushort4 kv = *(const ushort4*)(kfp + (size_t)lrow * FDIM + k0 + lk);
    __syncthreads();
    Qs[lk + 0][lrow] = bf2f(qv.x);
    Qs[lk + 1][lrow] = bf2f(qv.y);
    Qs[lk + 2][lrow] = bf2f(qv.z);
    Qs[lk + 3][lrow] = bf2f(qv.w);
    Ks[lk + 0][lrow] = bf2f(kv.x);
    Ks[lk + 1][lrow] = bf2f(kv.y);
    Ks[lk + 2][lrow] = bf2f(kv.z);
    Ks[lk + 3][lrow] = bf2f(kv.w);
    __syncthreads();
#pragma unroll
    for (int kk = 0; kk < 16; ++kk) {
      float4 a4 = *(const float4*)&Qs[kk][i0];
      float4 b4 = *(const float4*)&Ks[kk][j0];
      float a[4] = {a4.x, a4.y, a4.z, a4.w};
      float bq[4] = {b4.x, b4.y, b4.z, b4.w};
#pragma unroll
      for (int r = 0; r < 4; ++r)
#pragma unroll
        for (int cc = 0; cc < 4; ++cc) sacc[r][cc] += a[r] * bq[cc];
    }
  }
  __syncthreads();
#pragma unroll
  for (int r = 0; r < 4; ++r)
#pragma unroll
    for (int cc = 0; cc < 4; ++cc)
      St[j0 + cc][i0 + r] = (j0 + cc <= i0 + r) ? sacc[r][cc] : 0.f;
  __syncthreads();
  if (t < CHUNK) {
    float rs = 0.f;
#pragma unroll 8
    for (int j = 0; j < CHUNK; ++j) rs += St[j][t];
    den_l[t] = den + rs;
  }
  __syncthreads();

  // Phase D: num += S * V
#pragma unroll 4
  for (int j = 0; j < CHUNK; ++j) {
    float4 a4 = *(const float4*)&St[j][i0];
    float4 v4 = *(const float4*)&Vs[j][d0];
    float a[4] = {a4.x, a4.y, a4.z, a4.w};
    float vq[4] = {v4.x, v4.y, v4.z, v4.w};
#pragma unroll
    for (int r = 0; r < 4; ++r)
#pragma unroll
      for (int cc = 0; cc < 4; ++cc) acc[r][cc] += a[r] * vq[cc];
  }

  // Phase E: normalize + write
#pragma unroll
  for (int r = 0; r < 4; ++r) {
    float dl = den_l[i0 + r];
    float w = SCALE_F / (SCALE_F * dl + EPS_D);
    float4 o = {acc[r][0] * w, acc[r][1] * w, acc[r][2] * w, acc[r][3] * w};
    int rowg = (s0 + i0 + r) * BATCH + b;
    *(float4*)(attnvec + (size_t)rowg * DMODEL + n * DHEAD + d0) = o;
  }
}

// out = LN(h + attn_out) * gamma + beta
__global__ __launch_bounds__(256) void ln_kernel(
    const float* __restrict__ h, const float* __restrict__ ao,
    const float* __restrict__ gamma, const float* __restrict__ beta,
    float* __restrict__ out) {
  const int r = blockIdx.x, t = threadIdx.x;
  const float* hr = h + (size_t)r * DMODEL;
  const float* ar = ao + (size_t)r * DMODEL;
  float4 xh = *(const float4*)(hr + t * 4);
  float4 xa = *(const float4*)(ar + t * 4);
  float4 x = {xh.x + xa.x, xh.y + xa.y, xh.z + xa.z, xh.w + xa.w};
  float sum = x.x + x.y + x.z + x.w;
  float sq = x.x * x.x + x.y * x.y + x.z * x.z + x.w * x.w;
#pragma unroll
  for (int o = 32; o >= 1; o >>= 1) {
    sum += __shfl_xor(sum, o);
    sq += __shfl_xor(sq, o);
  }
  __shared__ float s_sum[4], s_sq[4];
  int w = t >> 6;
  if ((t & 63) == 0) { s_sum[w] = sum; s_sq[w] = sq; }
  __syncthreads();
  sum = s_sum[0] + s_sum[1] + s_sum[2] + s_sum[3];
  sq = s_sq[0] + s_sq[1] + s_sq[2] + s_sq[3];
  float mean = sum * (1.0f / DMODEL);
  float var = sq * (1.0f / DMODEL) - mean * mean;
  float rstd = rsqrtf(var + EPS_LN);
  float4 g = *(const float4*)(gamma + t * 4);
  float4 bb = *(const float4*)(beta + t * 4);
  float4 o4 = {g.x * (x.x - mean) * rstd + bb.x,
               g.y * (x.y - mean) * rstd + bb.y,
               g.z * (x.z - mean) * rstd + bb.z,
               g.w * (x.w - mean) * rstd + bb.w};
  *(float4*)(out + (size_t)r * DMODEL + t * 4) = o4;
}

extern "C" void kernel_launch(void* const* d_in, const int* in_sizes, int n_in,
                              void* d_out, int out_size, void* d_ws, size_t ws_size,
                              hipStream_t stream) {
  const float* h = (const float*)d_in[0];
  const float* Wq = (const float*)d_in[1];
  const float* Wkv = (const float*)d_in[2];
  const float* Wo = (const float*)d_in[3];
  const float* gamma = (const float*)d_in[4];
  const float* beta = (const float*)d_in[5];
  float* out = (float*)d_out;

  float* ws = (float*)d_ws;
  float* qproj = ws;                          // [3072][1024]
  float* kvproj = qproj + 3145728;            // [3072][2048]
  u16* qfeat = (u16*)(kvproj + 6291456);      // [2][16][1536][384] bf16
  u16* kfeat = qfeat + 18874368;              // same
  float* vbuf = (float*)(kfeat + 18874368);   // [2][16][1536][64]
  float* kvstate = vbuf + 3145728;            // [2][16][24][384][64]
  float* ksumst = kvstate + 18874368;         // [2][16][24][384]
  float* attnvec = ksumst + 294912;           // [3072][1024]
  float* attnout = qproj;                     // reuse (qproj dead after dpfp)

  hipLaunchKernelGGL(gemm_nt_f32, dim3(16, 48), dim3(256), 0, stream,
                     h, Wq, qproj, ROWS, 1024, 1024);
  hipLaunchKernelGGL(gemm_nt_f32, dim3(32, 48), dim3(256), 0, stream,
                     h, Wkv, kvproj, ROWS, 2048, 1024);
  hipLaunchKernelGGL(dpfp_kernel, dim3(16, 2, 1536), dim3(128), 0, stream,
                     qproj, 1024, 0, qfeat, (const float*)nullptr, (float*)nullptr);
  hipLaunchKernelGGL(dpfp_kernel, dim3(16, 2, 1536), dim3(128), 0, stream,
                     kvproj, 2048, 0, kfeat, kvproj, vbuf);
  hipLaunchKernelGGL(chunk_kv_kernel, dim3(24, 16, 2), dim3(256), 0, stream,
                     kfeat, vbuf, kvstate);
  hipLaunchKernelGGL(ksum_kernel, dim3(24, 16, 2), dim3(384), 0, stream,
                     kfeat, ksumst);
  hipLaunchKernelGGL(scan_kernel, dim3(3120), dim3(256), 0, stream,
                     kvstate, ksumst);
  hipLaunchKernelGGL(attn_kernel, dim3(24, 16, 2), dim3(256), 0, stream,
                     qfeat, kfeat, vbuf, kvstate, ksumst, attnvec);
  hipLaunchKernelGGL(gemm_nt_f32, dim3(16, 48), dim3(256), 0, stream,
                     attnvec, Wo, attnout, ROWS, 1024, 1024);
  hipLaunchKernelGGL(ln_kernel, dim3(3072), dim3(256), 0, stream,
                     h, attnout, gamma, beta, out);
}

// Round 2
// 346.996 us; speedup vs baseline: 1.7692x; 1.7692x over previous
//
#include <hip/hip_runtime.h>
#include <hip/hip_bf16.h>

#define S_LEN 1536
#define BATCH 2
#define DMODEL 1024
#define NHEAD 16
#define DHEAD 64
#define FDIM 384          // 2*DHEAD*N_ROLL
#define CHUNK 64
#define NCHUNK 24         // S_LEN / CHUNK
#define ROWS (S_LEN*BATCH)
#define SCALE_F 0.125f
#define EPS_D 1e-5f
#define EPS_LN 1e-5f

typedef unsigned short u16;
typedef __attribute__((ext_vector_type(8))) __bf16 bf16x8;
typedef __attribute__((ext_vector_type(4))) float f32x4;

static __device__ __forceinline__ float bf2f(u16 a) {
  return __uint_as_float(((unsigned)a) << 16);
}
static __device__ __forceinline__ u16 f2bf(float x) {
  unsigned u = __float_as_uint(x);
  unsigned r = (u + 0x7FFFu + ((u >> 16) & 1u)) >> 16;
  return (u16)r;
}
static __device__ __forceinline__ void gload_lds16(const void* g, void* l) {
  __builtin_amdgcn_global_load_lds(
      (const __attribute__((address_space(1))) void*)g,
      (__attribute__((address_space(3))) void*)l, 16, 0, 0);
}

// f32 -> bf16 convert, 4 elems/thread
__global__ __launch_bounds__(256) void cvt_bf16(
    const float* __restrict__ in, u16* __restrict__ out, int n4) {
  int i = blockIdx.x * 256 + threadIdx.x;
  if (i < n4) {
    float4 v = ((const float4*)in)[i];
    ushort4 o = {f2bf(v.x), f2bf(v.y), f2bf(v.z), f2bf(v.w)};
    ((ushort4*)out)[i] = o;
  }
}

// C[M][N] = A[M][K] * B[N][K]^T, A/B bf16, C f32. M%128==N%128==K%32==0.
// m97 structure: 128x128 tile, BK=32, 4 waves (2x2 of 64x64), 16B global_load_lds.
__global__ __launch_bounds__(256) void gemm_bf16_mfma(
    const u16* __restrict__ A, const u16* __restrict__ B,
    float* __restrict__ C, int M, int N, int K) {
  __shared__ u16 As[128 * 32];
  __shared__ u16 Bs[128 * 32];
  const int t = threadIdx.x;
  const int l = t & 63, w = t >> 6;
  const int m0 = blockIdx.y * 128, n0 = blockIdx.x * 128;
  const int wm = (w >> 1) * 64, wn = (w & 1) * 64;

  f32x4 acc[4][4];
#pragma unroll
  for (int i = 0; i < 4; ++i)
#pragma unroll
    for (int j = 0; j < 4; ++j) acc[i][j] = (f32x4)0.f;

  const size_t Kb = (size_t)K * 2;  // row stride bytes
  // staging: LDS byte o = c*4096 + w*1024 + l*16 ; row r=o>>6, kbyte=o&63
  const int o_lo = w * 1024 + l * 16;
  const int o_hi = 4096 + w * 1024 + l * 16;
  const int r_lo = o_lo >> 6, kb_lo = o_lo & 63;
  const int r_hi = o_hi >> 6, kb_hi = o_hi & 63;

  const char* Ap0 = (const char*)A + (size_t)(m0 + r_lo) * Kb + kb_lo;
  const char* Ap1 = (const char*)A + (size_t)(m0 + r_hi) * Kb + kb_hi;
  const char* Bp0 = (const char*)B + (size_t)(n0 + r_lo) * Kb + kb_lo;
  const char* Bp1 = (const char*)B + (size_t)(n0 + r_hi) * Kb + kb_hi;
  u16* AsB0 = As + (w * 1024) / 2;          // wave-uniform LDS bases
  u16* AsB1 = As + (4096 + w * 1024) / 2;
  u16* BsB0 = Bs + (w * 1024) / 2;
  u16* BsB1 = Bs + (4096 + w * 1024) / 2;

  const int fr = l & 15, ko = (l >> 4) * 8;  // fragment row / k-offset (elems)

  for (int k0 = 0; k0 < K; k0 += 32) {
    __syncthreads();
    gload_lds16(Ap0, AsB0);
    gload_lds16(Ap1, AsB1);
    gload_lds16(Bp0, BsB0);
    gload_lds16(Bp1, BsB1);
    Ap0 += 64; Ap1 += 64; Bp0 += 64; Bp1 += 64;
    __syncthreads();
    bf16x8 a[4], b[4];
#pragma unroll
    for (int m = 0; m < 4; ++m)
      a[m] = *(const bf16x8*)&As[(wm + m * 16 + fr) * 32 + ko];
#pragma unroll
    for (int n = 0; n < 4; ++n)
      b[n] = *(const bf16x8*)&Bs[(wn + n * 16 + fr) * 32 + ko];
#pragma unroll
    for (int m = 0; m < 4; ++m)
#pragma unroll
      for (int n = 0; n < 4; ++n)
        acc[m][n] = __builtin_amdgcn_mfma_f32_16x16x32_bf16(a[m], b[n], acc[m][n], 0, 0, 0);
  }

  // C/D layout (m89/m91 verified): col = lane&15, row = (lane>>4)*4 + reg
  const int cr = (l >> 4) * 4, ccol = l & 15;
#pragma unroll
  for (int m = 0; m < 4; ++m)
#pragma unroll
    for (int n = 0; n < 4; ++n)
#pragma unroll
      for (int j = 0; j < 4; ++j)
        C[(size_t)(m0 + wm + m * 16 + cr + j) * N + (n0 + wn + n * 16 + ccol)] =
            acc[m][n][j];
}

// DPFP: x[64] -> y[128]=[relu(x),relu(-x)] -> feat[384]: y[j]*y[(j-i)&127], i=1..3
// feat layout: [B][NHEAD][S][FDIM] bf16. Optionally copies v out of kvproj.
__global__ __launch_bounds__(128) void dpfp_kernel(
    const float* __restrict__ proj, int ldp, int col0,
    u16* __restrict__ feat,
    const float* __restrict__ vsrc, float* __restrict__ vdst) {
  const int t = threadIdx.x;
  const int n = blockIdx.x, b = blockIdx.y, s = blockIdx.z;
  const int r = s * BATCH + b;
  __shared__ float y[128];
  float x = proj[(size_t)r * ldp + col0 + n * DHEAD + (t & 63)];
  y[t] = fmaxf(t < 64 ? x : -x, 0.0f);
  __syncthreads();
  u16* outp = feat + ((size_t)(b * NHEAD + n) * S_LEN + s) * FDIM;
  float yt = y[t];
#pragma unroll
  for (int i = 1; i <= 3; ++i)
    outp[(i - 1) * 128 + t] = f2bf(yt * y[(t - i) & 127]);
  if (vsrc && t < 64)
    vdst[((size_t)(b * NHEAD + n) * S_LEN + s) * DHEAD + t] =
        vsrc[(size_t)r * 2048 + 1024 + n * DHEAD + t];
}

// Per-chunk KV outer-product sums: KV_c[f][d] = sum_{j in chunk} kf[j][f]*v[j][d]
__global__ __launch_bounds__(256) void chunk_kv_kernel(
    const u16* __restrict__ kf, const float* __restrict__ vbuf,
    float* __restrict__ kvstate) {
  const int t = threadIdx.x;
  const int c = blockIdx.x, n = blockIdx.y, b = blockIdx.z;
  const int bn = b * NHEAD + n;
  const u16* kfp = kf + ((size_t)bn * S_LEN + c * CHUNK) * FDIM;
  const float* vp = vbuf + ((size_t)bn * S_LEN + c * CHUNK) * DHEAD;
  __shared__ float kfs[FDIM];
  __shared__ float vs[DHEAD];
  const int f0 = (t >> 4) * 24, d0 = (t & 15) << 2;
  float acc[24][4] = {};
  for (int j = 0; j < CHUNK; ++j) {
    __syncthreads();
    for (int e = t; e < FDIM; e += 256) kfs[e] = bf2f(kfp[(size_t)j * FDIM + e]);
    if (t < DHEAD) vs[t] = vp[(size_t)j * DHEAD + t];
    __syncthreads();
    float4 vv = *(const float4*)&vs[d0];
#pragma unroll
    for (int u = 0; u < 6; ++u) {
      float4 kq = *(const float4*)&kfs[f0 + u * 4];
      float kk[4] = {kq.x, kq.y, kq.z, kq.w};
#pragma unroll
      for (int q = 0; q < 4; ++q) {
        acc[u * 4 + q][0] += kk[q] * vv.x;
        acc[u * 4 + q][1] += kk[q] * vv.y;
        acc[u * 4 + q][2] += kk[q] * vv.z;
        acc[u * 4 + q][3] += kk[q] * vv.w;
      }
    }
  }
  float* outp = kvstate + ((size_t)bn * NCHUNK + c) * (FDIM * DHEAD);
#pragma unroll
  for (int ff = 0; ff < 24; ++ff) {
    float4 o = {acc[ff][0], acc[ff][1], acc[ff][2], acc[ff][3]};
    *(float4*)(outp + (size_t)(f0 + ff) * DHEAD + d0) = o;
  }
}

// Per-chunk feature sums: Ksum_c[f] = sum_{j in chunk} kf[j][f]
__global__ __launch_bounds__(384) void ksum_kernel(
    const u16* __restrict__ kf, float* __restrict__ ksumst) {
  const int f = threadIdx.x;
  const int c = blockIdx.x, n = blockIdx.y, b = blockIdx.z;
  const int bn = b * NHEAD + n;
  const u16* kfp = kf + ((size_t)bn * S_LEN + c * CHUNK) * FDIM + f;
  float acc = 0.f;
  for (int j = 0; j < CHUNK; ++j) acc += bf2f(kfp[(size_t)j * FDIM]);
  ksumst[((size_t)bn * NCHUNK + c) * FDIM + f] = acc;
}

// Exclusive prefix over chunks, elementwise, in place.
__global__ __launch_bounds__(256) void scan_kernel(
    float* __restrict__ kvstate, float* __restrict__ ksumst) {
  const int bid = blockIdx.x;
  if (bid < 3072) {
    int gid = bid * 256 + threadIdx.x;      // 32*24576 elements
    int bn = gid / 24576, e = gid % 24576;
    float* base = kvstate + (size_t)bn * NCHUNK * 24576 + e;
    float a = 0.f;
    for (int c = 0; c < NCHUNK; ++c) {
      float x = base[(size_t)c * 24576];
      base[(size_t)c * 24576] = a;
      a += x;
    }
  } else {
    int gid = (bid - 3072) * 256 + threadIdx.x;  // 32*384 elements
    int bn = gid / FDIM, f = gid % FDIM;
    float* base = ksumst + (size_t)bn * NCHUNK * FDIM + f;
    float a = 0.f;
    for (int c = 0; c < NCHUNK; ++c) {
      float x = base[(size_t)c * FDIM];
      base[(size_t)c * FDIM] = a;
      a += x;
    }
  }
}

// Fused per-chunk attention: inter (qf·KVprefix, qf·Ksumprefix) + intra
// (causal 64x64 scores) + normalization. Writes attnvec (bf16) rows
// [s*B+b][n*64+d].
__global__ __launch_bounds__(256) void attn_kernel(
    const u16* __restrict__ qf, const u16* __restrict__ kf,
    const float* __restrict__ vbuf, const float* __restrict__ kvstate,
    const float* __restrict__ ksumst, u16* __restrict__ attnvec) {
  const int t = threadIdx.x;
  const int c = blockIdx.x, n = blockIdx.y, b = blockIdx.z;
  const int bn = b * NHEAD + n;
  const int s0 = c * CHUNK;
  const u16* qfp = qf + ((size_t)bn * S_LEN + s0) * FDIM;
  const u16* kfp = kf + ((size_t)bn * S_LEN + s0) * FDIM;
  const float* vp = vbuf + ((size_t)bn * S_LEN + s0) * DHEAD;
  const float* kvp = kvstate + ((size_t)bn * NCHUNK + c) * (FDIM * DHEAD);
  const float* ksp = ksumst + ((size_t)bn * NCHUNK + c) * FDIM;

  __shared__ float Qs[16][68];
  __shared__ float Ks[16][68];       // also reused as KV-prefix slab
  __shared__ float St[CHUNK][68];    // transposed scores St[j][i]
  __shared__ float Vs[CHUNK][68];
  __shared__ float ks_l[FDIM];
  __shared__ float den_l[CHUNK];

  for (int e = t; e < FDIM; e += 256) ks_l[e] = ksp[e];
  for (int i = t; i < CHUNK * 16; i += 256) {
    int j = i >> 4, dq = (i & 15) << 2;
    *(float4*)&Vs[j][dq] = *(const float4*)(vp + (size_t)j * DHEAD + dq);
  }

  const int tx = t & 15, ty = t >> 4;
  const int i0 = ty << 2, d0 = tx << 2, j0 = tx << 2;
  const int lrow = t >> 2, lk = (t & 3) << 2;

  float acc[4][4] = {};
  float den = 0.f;

  // Phase B: inter part, num += Qf*KVprefix ; den += Qf*Ksumprefix
  for (int k0 = 0; k0 < FDIM; k0 += 16) {
    ushort4 qv = *(const ushort4*)(qfp + (size_t)lrow * FDIM + k0 + lk);
    float4 kvv = *(const float4*)(kvp + (size_t)(k0 + (t >> 4)) * DHEAD + ((t & 15) << 2));
    __syncthreads();
    Qs[lk + 0][lrow] = bf2f(qv.x);
    Qs[lk + 1][lrow] = bf2f(qv.y);
    Qs[lk + 2][lrow] = bf2f(qv.z);
    Qs[lk + 3][lrow] = bf2f(qv.w);
    *(float4*)&Ks[t >> 4][(t & 15) << 2] = kvv;
    __syncthreads();
#pragma unroll
    for (int kk = 0; kk < 16; ++kk) {
      float4 a4 = *(const float4*)&Qs[kk][i0];
      float4 b4 = *(const float4*)&Ks[kk][d0];
      float a[4] = {a4.x, a4.y, a4.z, a4.w};
      float bq[4] = {b4.x, b4.y, b4.z, b4.w};
#pragma unroll
      for (int r = 0; r < 4; ++r)
#pragma unroll
        for (int cc = 0; cc < 4; ++cc) acc[r][cc] += a[r] * bq[cc];
    }
    if (t < CHUNK) {
#pragma unroll
      for (int kk = 0; kk < 16; ++kk) den += Qs[kk][t] * ks_l[k0 + kk];
    }
  }

  // Phase C: intra scores (causal within chunk), stored transposed
  float sacc[4][4] = {};
  for (int k0 = 0; k0 < FDIM; k0 += 16) {
    ushort4 qv = *(const ushort4*)(qfp + (size_t)lrow * FDIM + k0 + lk);
    ushort4 kv = *(const ushort4*)(kfp + (size_t)lrow * FDIM + k0 + lk);
    __syncthreads();
    Qs[lk + 0][lrow] = bf2f(qv.x);
    Qs[lk + 1][lrow] = bf2f(qv.y);
    Qs[lk + 2][lrow] = bf2f(qv.z);
    Qs[lk + 3][lrow] = bf2f(qv.w);
    Ks[lk + 0][lrow] = bf2f(kv.x);
    Ks[lk + 1][lrow] = bf2f(kv.y);
    Ks[lk + 2][lrow] = bf2f(kv.z);
    Ks[lk + 3][lrow] = bf2f(kv.w);
    __syncthreads();
#pragma unroll
    for (int kk = 0; kk < 16; ++kk) {
      float4 a4 = *(const float4*)&Qs[kk][i0];
      float4 b4 = *(const float4*)&Ks[kk][j0];
      float a[4] = {a4.x, a4.y, a4.z, a4.w};
      float bq[4] = {b4.x, b4.y, b4.z, b4.w};
#pragma unroll
      for (int r = 0; r < 4; ++r)
#pragma unroll
        for (int cc = 0; cc < 4; ++cc) sacc[r][cc] += a[r] * bq[cc];
    }
  }
  __syncthreads();
#pragma unroll
  for (int r = 0; r < 4; ++r)
#pragma unroll
    for (int cc = 0; cc < 4; ++cc)
      St[j0 + cc][i0 + r] = (j0 + cc <= i0 + r) ? sacc[r][cc] : 0.f;
  __syncthreads();
  if (t < CHUNK) {
    float rs = 0.f;
#pragma unroll 8
    for (int j = 0; j < CHUNK; ++j) rs += St[j][t];
    den_l[t] = den + rs;
  }
  __syncthreads();

  // Phase D: num += S * V
#pragma unroll 4
  for (int j = 0; j < CHUNK; ++j) {
    float4 a4 = *(const float4*)&St[j][i0];
    float4 v4 = *(const float4*)&Vs[j][d0];
    float a[4] = {a4.x, a4.y, a4.z, a4.w};
    float vq[4] = {v4.x, v4.y, v4.z, v4.w};
#pragma unroll
    for (int r = 0; r < 4; ++r)
#pragma unroll
      for (int cc = 0; cc < 4; ++cc) acc[r][cc] += a[r] * vq[cc];
  }

  // Phase E: normalize + write (bf16)
#pragma unroll
  for (int r = 0; r < 4; ++r) {
    float dl = den_l[i0 + r];
    float w = SCALE_F / (SCALE_F * dl + EPS_D);
    ushort4 o = {f2bf(acc[r][0] * w), f2bf(acc[r][1] * w),
                 f2bf(acc[r][2] * w), f2bf(acc[r][3] * w)};
    int rowg = (s0 + i0 + r) * BATCH + b;
    *(ushort4*)(attnvec + (size_t)rowg * DMODEL + n * DHEAD + d0) = o;
  }
}

// out = LN(h + attn_out) * gamma + beta
__global__ __launch_bounds__(256) void ln_kernel(
    const float* __restrict__ h, const float* __restrict__ ao,
    const float* __restrict__ gamma, const float* __restrict__ beta,
    float* __restrict__ out) {
  const int r = blockIdx.x, t = threadIdx.x;
  const float* hr = h + (size_t)r * DMODEL;
  const float* ar = ao + (size_t)r * DMODEL;
  float4 xh = *(const float4*)(hr + t * 4);
  float4 xa = *(const float4*)(ar + t * 4);
  float4 x = {xh.x + xa.x, xh.y + xa.y, xh.z + xa.z, xh.w + xa.w};
  float sum = x.x + x.y + x.z + x.w;
  float sq = x.x * x.x + x.y * x.y + x.z * x.z + x.w * x.w;
#pragma unroll
  for (int o = 32; o >= 1; o >>= 1) {
    sum += __shfl_xor(sum, o);
    sq += __shfl_xor(sq, o);
  }
  __shared__ float s_sum[4], s_sq[4];
  int w = t >> 6;
  if ((t & 63) == 0) { s_sum[w] = sum; s_sq[w] = sq; }
  __syncthreads();
  sum = s_sum[0] + s_sum[1] + s_sum[2] + s_sum[3];
  sq = s_sq[0] + s_sq[1] + s_sq[2] + s_sq[3];
  float mean = sum * (1.0f / DMODEL);
  float var = sq * (1.0f / DMODEL) - mean * mean;
  float rstd = rsqrtf(var + EPS_LN);
  float4 g = *(const float4*)(gamma + t * 4);
  float4 bb = *(const float4*)(beta + t * 4);
  float4 o4 = {g.x * (x.x - mean) * rstd + bb.x,
               g.y * (x.y - mean) * rstd + bb.y,
               g.z * (x.z - mean) * rstd + bb.z,
               g.w * (x.w - mean) * rstd + bb.w};
  *(float4*)(out + (size_t)r * DMODEL + t * 4) = o4;
}

extern "C" void kernel_launch(void* const* d_in, const int* in_sizes, int n_in,
                              void* d_out, int out_size, void* d_ws, size_t ws_size,
                              hipStream_t stream) {
  const float* h = (const float*)d_in[0];
  const float* Wq = (const float*)d_in[1];
  const float* Wkv = (const float*)d_in[2];
  const float* Wo = (const float*)d_in[3];
  const float* gamma = (const float*)d_in[4];
  const float* beta = (const float*)d_in[5];
  float* out = (float*)d_out;

  float* ws = (float*)d_ws;
  float* qproj = ws;                          // [3072][1024] f32
  float* kvproj = qproj + 3145728;            // [3072][2048] f32
  u16* qfeat = (u16*)(kvproj + 6291456);      // [2][16][1536][384] bf16
  u16* kfeat = qfeat + 18874368;              // same
  float* vbuf = (float*)(kfeat + 18874368);   // [2][16][1536][64] f32
  float* kvstate = vbuf + 3145728;            // [2][16][24][384][64] f32
  float* ksumst = kvstate + 18874368;         // [2][16][24][384] f32
  u16* attnvec = (u16*)(ksumst + 294912);     // [3072][1024] bf16
  u16* Wo_bf = attnvec + 3145728;             // [1024][1024] bf16
  float* attnout = qproj;                     // reuse (qproj dead after dpfp)
  // bf16 inputs live in the (not yet written) kvstate slab
  u16* h_bf = (u16*)kvstate;                  // [3072][1024] bf16
  u16* Wq_bf = h_bf + 3145728;                // [1024][1024] bf16
  u16* Wkv_bf = Wq_bf + 1048576;              // [2048][1024] bf16

  hipLaunchKernelGGL(cvt_bf16, dim3(3072), dim3(256), 0, stream, h, h_bf, 786432);
  hipLaunchKernelGGL(cvt_bf16, dim3(1024), dim3(256), 0, stream, Wq, Wq_bf, 262144);
  hipLaunchKernelGGL(cvt_bf16, dim3(2048), dim3(256), 0, stream, Wkv, Wkv_bf, 524288);
  hipLaunchKernelGGL(cvt_bf16, dim3(1024), dim3(256), 0, stream, Wo, Wo_bf, 262144);

  hipLaunchKernelGGL(gemm_bf16_mfma, dim3(8, 24), dim3(256), 0, stream,
                     h_bf, Wq_bf, qproj, ROWS, 1024, 1024);
  hipLaunchKernelGGL(gemm_bf16_mfma, dim3(16, 24), dim3(256), 0, stream,
                     h_bf, Wkv_bf, kvproj, ROWS, 2048, 1024);
  hipLaunchKernelGGL(dpfp_kernel, dim3(16, 2, 1536), dim3(128), 0, stream,
                     qproj, 1024, 0, qfeat, (const float*)nullptr, (float*)nullptr);
  hipLaunchKernelGGL(dpfp_kernel, dim3(16, 2, 1536), dim3(128), 0, stream,
                     kvproj, 2048, 0, kfeat, kvproj, vbuf);
  hipLaunchKernelGGL(chunk_kv_kernel, dim3(24, 16, 2), dim3(256), 0, stream,
                     kfeat, vbuf, kvstate);
  hipLaunchKernelGGL(ksum_kernel, dim3(24, 16, 2), dim3(384), 0, stream,
                     kfeat, ksumst);
  hipLaunchKernelGGL(scan_kernel, dim3(3120), dim3(256), 0, stream,
                     kvstate, ksumst);
  hipLaunchKernelGGL(attn_kernel, dim3(24, 16, 2), dim3(256), 0, stream,
                     qfeat, kfeat, vbuf, kvstate, ksumst, attnvec);
  hipLaunchKernelGGL(gemm_bf16_mfma, dim3(8, 24), dim3(256), 0, stream,
                     attnvec, Wo_bf, attnout, ROWS, 1024, 1024);
  hipLaunchKernelGGL(ln_kernel, dim3(3072), dim3(256), 0, stream,
                     h, attnout, gamma, beta, out);
}

// Round 3
// 208.529 us; speedup vs baseline: 2.9440x; 1.6640x over previous
//
#include <hip/hip_runtime.h>
#include <hip/hip_bf16.h>

#define S_LEN 1536
#define BATCH 2
#define DMODEL 1024
#define NHEAD 16
#define DHEAD 64
#define FDIM 384          // 2*DHEAD*N_ROLL
#define CHUNK 64
#define NCHUNK 24         // S_LEN / CHUNK
#define ROWS (S_LEN*BATCH)
#define SCALE_F 0.125f
#define EPS_D 1e-5f
#define EPS_LN 1e-5f

typedef unsigned short u16;
typedef __attribute__((ext_vector_type(8))) __bf16 bf16x8;
typedef __attribute__((ext_vector_type(8))) unsigned short ushort8;
typedef __attribute__((ext_vector_type(4))) float f32x4;

static __device__ __forceinline__ float bf2f(u16 a) {
  return __uint_as_float(((unsigned)a) << 16);
}
static __device__ __forceinline__ u16 f2bf(float x) {
  unsigned u = __float_as_uint(x);
  unsigned r = (u + 0x7FFFu + ((u >> 16) & 1u)) >> 16;
  return (u16)r;
}
static __device__ __forceinline__ void gload_lds16(const void* g, void* l) {
  __builtin_amdgcn_global_load_lds(
      (const __attribute__((address_space(1))) void*)g,
      (__attribute__((address_space(3))) void*)l, 16, 0, 0);
}
#define MFMA(a, b, c) __builtin_amdgcn_mfma_f32_16x16x32_bf16(a, b, c, 0, 0, 0)

// f32 -> bf16 convert, 4 elems/thread
__global__ __launch_bounds__(256) void cvt_bf16(
    const float* __restrict__ in, u16* __restrict__ out, int n4) {
  int i = blockIdx.x * 256 + threadIdx.x;
  if (i < n4) {
    float4 v = ((const float4*)in)[i];
    ushort4 o = {f2bf(v.x), f2bf(v.y), f2bf(v.z), f2bf(v.w)};
    ((ushort4*)out)[i] = o;
  }
}

// C[M][N] = A[M][K]*B[N][K]^T, bf16 in / f32 out. 128x128 tile, BK=32, 4 waves.
__global__ __launch_bounds__(256) void gemm_bf16_mfma(
    const u16* __restrict__ A, const u16* __restrict__ B,
    float* __restrict__ C, int M, int N, int K) {
  __shared__ u16 As[128 * 32];
  __shared__ u16 Bs[128 * 32];
  const int t = threadIdx.x;
  const int l = t & 63, w = t >> 6;
  const int m0 = blockIdx.y * 128, n0 = blockIdx.x * 128;
  const int wm = (w >> 1) * 64, wn = (w & 1) * 64;

  f32x4 acc[4][4];
#pragma unroll
  for (int i = 0; i < 4; ++i)
#pragma unroll
    for (int j = 0; j < 4; ++j) acc[i][j] = (f32x4)0.f;

  const size_t Kb = (size_t)K * 2;
  const int o_lo = w * 1024 + l * 16;
  const int o_hi = 4096 + w * 1024 + l * 16;
  const int r_lo = o_lo >> 6, kb_lo = o_lo & 63;
  const int r_hi = o_hi >> 6, kb_hi = o_hi & 63;

  const char* Ap0 = (const char*)A + (size_t)(m0 + r_lo) * Kb + kb_lo;
  const char* Ap1 = (const char*)A + (size_t)(m0 + r_hi) * Kb + kb_hi;
  const char* Bp0 = (const char*)B + (size_t)(n0 + r_lo) * Kb + kb_lo;
  const char* Bp1 = (const char*)B + (size_t)(n0 + r_hi) * Kb + kb_hi;
  u16* AsB0 = As + (w * 1024) / 2;
  u16* AsB1 = As + (4096 + w * 1024) / 2;
  u16* BsB0 = Bs + (w * 1024) / 2;
  u16* BsB1 = Bs + (4096 + w * 1024) / 2;

  const int fr = l & 15, ko = (l >> 4) * 8;

  for (int k0 = 0; k0 < K; k0 += 32) {
    __syncthreads();
    gload_lds16(Ap0, AsB0);
    gload_lds16(Ap1, AsB1);
    gload_lds16(Bp0, BsB0);
    gload_lds16(Bp1, BsB1);
    Ap0 += 64; Ap1 += 64; Bp0 += 64; Bp1 += 64;
    __syncthreads();
    bf16x8 a[4], b[4];
#pragma unroll
    for (int m = 0; m < 4; ++m)
      a[m] = *(const bf16x8*)&As[(wm + m * 16 + fr) * 32 + ko];
#pragma unroll
    for (int n = 0; n < 4; ++n)
      b[n] = *(const bf16x8*)&Bs[(wn + n * 16 + fr) * 32 + ko];
#pragma unroll
    for (int m = 0; m < 4; ++m)
#pragma unroll
      for (int n = 0; n < 4; ++n)
        acc[m][n] = MFMA(a[m], b[n], acc[m][n]);
  }

  const int cr = (l >> 4) * 4, ccol = l & 15;
#pragma unroll
  for (int m = 0; m < 4; ++m)
#pragma unroll
    for (int n = 0; n < 4; ++n)
#pragma unroll
      for (int j = 0; j < 4; ++j)
        C[(size_t)(m0 + wm + m * 16 + cr + j) * N + (n0 + wn + n * 16 + ccol)] =
            acc[m][n][j];
}

// 64x64 tile, BK=32, 4 waves each 16(m)x64(n). For skinny GEMMs (more blocks).
__global__ __launch_bounds__(256) void gemm64_bf16(
    const u16* __restrict__ A, const u16* __restrict__ B,
    float* __restrict__ C, int M, int N, int K) {
  __shared__ u16 As[64 * 32];
  __shared__ u16 Bs[64 * 32];
  const int t = threadIdx.x;
  const int l = t & 63, w = t >> 6;
  const int m0 = blockIdx.y * 64, n0 = blockIdx.x * 64;
  const int fr = l & 15, kg = l >> 4;
  const size_t Kb = (size_t)K * 2;
  const int o = t * 16, r = o >> 6, kb = o & 63;
  const char* Ap = (const char*)A + (size_t)(m0 + r) * Kb + kb;
  const char* Bp = (const char*)B + (size_t)(n0 + r) * Kb + kb;
  u16* AsB = As + (w * 1024) / 2;
  u16* BsB = Bs + (w * 1024) / 2;
  f32x4 acc[4];
#pragma unroll
  for (int i = 0; i < 4; ++i) acc[i] = (f32x4)0.f;
  for (int k0 = 0; k0 < K; k0 += 32) {
    __syncthreads();
    gload_lds16(Ap, AsB);
    gload_lds16(Bp, BsB);
    Ap += 64; Bp += 64;
    __syncthreads();
    bf16x8 a = *(const bf16x8*)&As[(16 * w + fr) * 32 + kg * 8];
#pragma unroll
    for (int nt = 0; nt < 4; ++nt) {
      bf16x8 b = *(const bf16x8*)&Bs[(16 * nt + fr) * 32 + kg * 8];
      acc[nt] = MFMA(a, b, acc[nt]);
    }
  }
#pragma unroll
  for (int nt = 0; nt < 4; ++nt)
#pragma unroll
    for (int reg = 0; reg < 4; ++reg)
      C[(size_t)(m0 + 16 * w + 4 * kg + reg) * N + (n0 + 16 * nt + fr)] =
          acc[nt][reg];
}

// DPFP for q: per (n,b,s) block, writes qfeat [bn][s][384] bf16.
__global__ __launch_bounds__(128) void dpfp_q(
    const float* __restrict__ proj, u16* __restrict__ feat) {
  const int t = threadIdx.x;
  const int n = blockIdx.x, b = blockIdx.y, s = blockIdx.z;
  const int r = s * BATCH + b;
  __shared__ float y[128];
  float x = proj[(size_t)r * 3072 + n * DHEAD + (t & 63)];
  y[t] = fmaxf(t < 64 ? x : -x, 0.0f);
  __syncthreads();
  u16* outp = feat + ((size_t)(b * NHEAD + n) * S_LEN + s) * FDIM;
  float yt = y[t];
#pragma unroll
  for (int i = 1; i <= 3; ++i)
    outp[(i - 1) * 128 + t] = f2bf(yt * y[(t - i) & 127]);
}

// DPFP for k (+v): per (c, bn) block over 64 s-rows. Writes kfeat [bn][s][f],
// kfeatT [bn][f][s], vT [bn][d][s] (all bf16).
__global__ __launch_bounds__(256) void dpfp_k64(
    const float* __restrict__ proj, u16* __restrict__ kfeat,
    u16* __restrict__ kfeatT, u16* __restrict__ vTbf) {
  const int c = blockIdx.x, bn = blockIdx.y;
  const int b = bn >> 4, n = bn & 15;
  const int s0 = c * CHUNK;
  const int t = threadIdx.x;
  __shared__ float y[64][129];
  __shared__ float vs[64][65];
  const int j = t >> 2, dq = (t & 3) << 4;
  const float* kp = proj + (size_t)((s0 + j) * BATCH + b) * 3072 + n * DHEAD + dq;
  const float* vp = kp + (2048 - dq) + dq;  // cols 2048 + n*64 + dq
  // note: v cols are at 2048 + n*64 + d  (proj = [q(1024) | k(1024) | v(1024)])
#pragma unroll
  for (int u = 0; u < 4; ++u) {
    float4 xv = *(const float4*)(kp + 1024 + 4 * u);   // k at cols 1024+
    float4 vv = *(const float4*)(kp + 2048 + 4 * u);   // v at cols 2048+
    int d = dq + 4 * u;
    y[j][d + 0] = fmaxf(xv.x, 0.f); y[j][64 + d + 0] = fmaxf(-xv.x, 0.f);
    y[j][d + 1] = fmaxf(xv.y, 0.f); y[j][64 + d + 1] = fmaxf(-xv.y, 0.f);
    y[j][d + 2] = fmaxf(xv.z, 0.f); y[j][64 + d + 2] = fmaxf(-xv.z, 0.f);
    y[j][d + 3] = fmaxf(xv.w, 0.f); y[j][64 + d + 3] = fmaxf(-xv.w, 0.f);
    vs[j][d + 0] = vv.x; vs[j][d + 1] = vv.y;
    vs[j][d + 2] = vv.z; vs[j][d + 3] = vv.w;
  }
  __syncthreads();
  // kfeat normal: row j, f in [(t&3)*96, +96)
  {
    u16* orow = kfeat + ((size_t)bn * S_LEN + s0 + j) * FDIM;
    const int f0 = (t & 3) * 96;
    for (int fo = 0; fo < 96; fo += 4) {
      ushort4 o;
      unsigned short* op = (unsigned short*)&o;
#pragma unroll
      for (int e = 0; e < 4; ++e) {
        int f = f0 + fo + e, m = f & 127, sh = (f >> 7) + 1;
        op[e] = f2bf(y[j][m] * y[j][(m - sh) & 127]);
      }
      *(ushort4*)(orow + f0 + fo) = o;
    }
  }
  // kfeatT: col s = t&63, f rows strided by 4
  {
    const int s = t & 63, fb = t >> 6;
    for (int ff = fb; ff < FDIM; ff += 4) {
      int m = ff & 127, sh = (ff >> 7) + 1;
      kfeatT[((size_t)bn * FDIM + ff) * S_LEN + s0 + s] =
          f2bf(y[s][m] * y[s][(m - sh) & 127]);
    }
  }
  // vT: col s = t&63, d rows strided by 4
  {
    const int s = t & 63, db = t >> 6;
    for (int d = db; d < 64; d += 4)
      vTbf[((size_t)bn * 64 + d) * S_LEN + s0 + s] = f2bf(vs[s][d]);
  }
}

// Per-chunk KV sums via MFMA: KV_c[d][f] = sum_j v[j][d]*kf[j][f] (bf16 out),
// plus ksum_c[f] (f32). Grid (c, bn), 4 waves, wave w covers f in [96w,96w+96).
__global__ __launch_bounds__(256) void chunk_kv_mfma(
    const u16* __restrict__ kfT, const u16* __restrict__ vT,
    u16* __restrict__ kvstate, float* __restrict__ ksumst) {
  const int c = blockIdx.x, bn = blockIdx.y;
  const int s0 = c * CHUNK;
  const int t = threadIdx.x, l = t & 63, w = t >> 6;
  const int fr = l & 15, kg = l >> 4;
  const u16* vTp = vT + (size_t)bn * 64 * S_LEN + s0;
  const u16* kTp = kfT + (size_t)bn * FDIM * S_LEN + s0;

  f32x4 acc[4][6];
#pragma unroll
  for (int m = 0; m < 4; ++m)
#pragma unroll
    for (int nt = 0; nt < 6; ++nt) acc[m][nt] = (f32x4)0.f;
  float ks[6] = {0.f, 0.f, 0.f, 0.f, 0.f, 0.f};

#pragma unroll
  for (int ksi = 0; ksi < 2; ++ksi) {
    const int ko = ksi * 32 + kg * 8;
    bf16x8 a[4];
#pragma unroll
    for (int m = 0; m < 4; ++m)
      a[m] = *(const bf16x8*)(vTp + (size_t)(16 * m + fr) * S_LEN + ko);
#pragma unroll
    for (int nt = 0; nt < 6; ++nt) {
      const u16* bp = kTp + (size_t)(96 * w + 16 * nt + fr) * S_LEN + ko;
      bf16x8 bfrag = *(const bf16x8*)bp;
      ushort8 raw = *(const ushort8*)bp;
#pragma unroll
      for (int e = 0; e < 8; ++e) ks[nt] += bf2f(raw[e]);
#pragma unroll
      for (int m = 0; m < 4; ++m) acc[m][nt] = MFMA(a[m], bfrag, acc[m][nt]);
    }
  }
  // ksum reduce over kg groups (lanes ^16, ^32)
#pragma unroll
  for (int nt = 0; nt < 6; ++nt) {
    float x = ks[nt];
    x += __shfl_xor(x, 16);
    x += __shfl_xor(x, 32);
    ks[nt] = x;
  }
  if (l < 16) {
    float* kso = ksumst + (size_t)(bn * NCHUNK + c) * FDIM + 96 * w;
#pragma unroll
    for (int nt = 0; nt < 6; ++nt) kso[16 * nt + l] = ks[nt];
  }
  u16* outp = kvstate + (size_t)(bn * NCHUNK + c) * (64 * FDIM);
#pragma unroll
  for (int m = 0; m < 4; ++m)
#pragma unroll
    for (int nt = 0; nt < 6; ++nt)
#pragma unroll
      for (int reg = 0; reg < 4; ++reg) {
        int d = 16 * m + 4 * kg + reg, f = 96 * w + 16 * nt + fr;
        outp[(size_t)d * FDIM + f] = f2bf(acc[m][nt][reg]);
      }
}

// Exclusive prefix over chunks: kvstate bf16 (f32 accum) + ksumst f32, in place.
__global__ __launch_bounds__(256) void scan_kernel(
    u16* __restrict__ kvstate, float* __restrict__ ksumst) {
  const int bid = blockIdx.x;
  if (bid < 3072) {
    int gid = bid * 256 + threadIdx.x;      // 32 * 24576 elements
    int bn = gid / 24576, e = gid % 24576;
    u16* base = kvstate + (size_t)bn * NCHUNK * 24576 + e;
    float a = 0.f;
    for (int c = 0; c < NCHUNK; ++c) {
      float x = bf2f(base[(size_t)c * 24576]);
      base[(size_t)c * 24576] = f2bf(a);
      a += x;
    }
  } else {
    int gid = (bid - 3072) * 256 + threadIdx.x;  // 32 * 384 elements
    int bn = gid / FDIM, f = gid % FDIM;
    float* base = ksumst + (size_t)bn * NCHUNK * FDIM + f;
    float a = 0.f;
    for (int c = 0; c < NCHUNK; ++c) {
      float x = base[(size_t)c * FDIM];
      base[(size_t)c * FDIM] = a;
      a += x;
    }
  }
}

// Fused attention, MFMA. Grid (c, bn), 4 waves; wave w owns i-strip [16w,16w+16).
// Merged pass: n-tiles 0..3 = intra scores (kf), 4..7 = inter output (kvpre).
// Then mask+rowsum, S->LDS(bf16), S*vT accumulated into tiles 4..7.
__global__ __launch_bounds__(256) void attn_mfma(
    const u16* __restrict__ qf, const u16* __restrict__ kf,
    const u16* __restrict__ vT, const u16* __restrict__ kvpre,
    const float* __restrict__ kspre, u16* __restrict__ attnvec) {
  const int c = blockIdx.x, bn = blockIdx.y;
  const int b = bn >> 4, n = bn & 15;
  const int s0 = c * CHUNK;
  const int t = threadIdx.x, l = t & 63, w = t >> 6;
  const int fr = l & 15, kg = l >> 4;

  const u16* qfp = qf + ((size_t)bn * S_LEN + s0) * FDIM;
  const u16* kfp = kf + ((size_t)bn * S_LEN + s0) * FDIM;
  const u16* kvp = kvpre + (size_t)(bn * NCHUNK + c) * (64 * FDIM);
  const u16* vTp = vT + (size_t)bn * 64 * S_LEN + s0;
  const float* ksp = kspre + (size_t)(bn * NCHUNK + c) * FDIM;

  __shared__ u16 Sb[64][68];
  __shared__ float rs[64];
  __shared__ float dins[4][64];

  f32x4 acc[8];
#pragma unroll
  for (int i = 0; i < 8; ++i) acc[i] = (f32x4)0.f;

  const u16* arow = qfp + (size_t)(16 * w + fr) * FDIM + kg * 8;
#pragma unroll 4
  for (int k0 = 0; k0 < FDIM; k0 += 32) {
    bf16x8 a = *(const bf16x8*)(arow + k0);
#pragma unroll
    for (int nt = 0; nt < 4; ++nt) {
      bf16x8 bfrag = *(const bf16x8*)(kfp + (size_t)(16 * nt + fr) * FDIM + kg * 8 + k0);
      acc[nt] = MFMA(a, bfrag, acc[nt]);
    }
#pragma unroll
    for (int nt = 0; nt < 4; ++nt) {
      bf16x8 bfrag = *(const bf16x8*)(kvp + (size_t)(16 * nt + fr) * FDIM + kg * 8 + k0);
      acc[4 + nt] = MFMA(a, bfrag, acc[4 + nt]);
    }
  }

  // mask (j>i -> 0), rowsum, write S to LDS (bf16)
#pragma unroll
  for (int reg = 0; reg < 4; ++reg) {
    int i = 16 * w + 4 * kg + reg;
    float r = 0.f;
#pragma unroll
    for (int nt = 0; nt < 4; ++nt) {
      int jj = 16 * nt + fr;
      float sval = (jj <= i) ? acc[nt][reg] : 0.f;
      acc[nt][reg] = sval;
      r += sval;
    }
    r += __shfl_xor(r, 1); r += __shfl_xor(r, 2);
    r += __shfl_xor(r, 4); r += __shfl_xor(r, 8);
    if (fr == 0) rs[i] = r;
  }
#pragma unroll
  for (int nt = 0; nt < 4; ++nt)
#pragma unroll
    for (int reg = 0; reg < 4; ++reg)
      Sb[16 * w + 4 * kg + reg][16 * nt + fr] = f2bf(acc[nt][reg]);

  // inter denominator: wave w sums f in [96w, 96w+96) for row i = l
  {
    float d = 0.f;
    const u16* qrow = qfp + (size_t)l * FDIM + 96 * w;
    const float* kk = ksp + 96 * w;
    for (int u = 0; u < 12; ++u) {
      ushort8 qv = *(const ushort8*)(qrow + 8 * u);
#pragma unroll
      for (int e = 0; e < 8; ++e) d += bf2f(qv[e]) * kk[8 * u + e];
    }
    dins[w][l] = d;
  }

  __syncthreads();

  // phase D: acc[4..7] += S * vT
#pragma unroll
  for (int ksi = 0; ksi < 2; ++ksi) {
    const int ko = ksi * 32 + kg * 8;
    bf16x8 a = *(const bf16x8*)&Sb[16 * w + fr][ko];
#pragma unroll
    for (int nt = 0; nt < 4; ++nt) {
      bf16x8 bfrag = *(const bf16x8*)(vTp + (size_t)(16 * nt + fr) * S_LEN + ko);
      acc[4 + nt] = MFMA(a, bfrag, acc[4 + nt]);
    }
  }

  // normalize + store
#pragma unroll
  for (int reg = 0; reg < 4; ++reg) {
    int i = 16 * w + 4 * kg + reg;
    float den = rs[i] + dins[0][i] + dins[1][i] + dins[2][i] + dins[3][i];
    float sc = SCALE_F / (SCALE_F * den + EPS_D);
    int rowg = (s0 + i) * BATCH + b;
    u16* orow = attnvec + (size_t)rowg * DMODEL + n * DHEAD;
#pragma unroll
    for (int nt = 0; nt < 4; ++nt)
      orow[16 * nt + fr] = f2bf(acc[4 + nt][reg] * sc);
  }
}

// out = LN(h + attn_out) * gamma + beta
__global__ __launch_bounds__(256) void ln_kernel(
    const float* __restrict__ h, const float* __restrict__ ao,
    const float* __restrict__ gamma, const float* __restrict__ beta,
    float* __restrict__ out) {
  const int r = blockIdx.x, t = threadIdx.x;
  const float* hr = h + (size_t)r * DMODEL;
  const float* ar = ao + (size_t)r * DMODEL;
  float4 xh = *(const float4*)(hr + t * 4);
  float4 xa = *(const float4*)(ar + t * 4);
  float4 x = {xh.x + xa.x, xh.y + xa.y, xh.z + xa.z, xh.w + xa.w};
  float sum = x.x + x.y + x.z + x.w;
  float sq = x.x * x.x + x.y * x.y + x.z * x.z + x.w * x.w;
#pragma unroll
  for (int o = 32; o >= 1; o >>= 1) {
    sum += __shfl_xor(sum, o);
    sq += __shfl_xor(sq, o);
  }
  __shared__ float s_sum[4], s_sq[4];
  int w = t >> 6;
  if ((t & 63) == 0) { s_sum[w] = sum; s_sq[w] = sq; }
  __syncthreads();
  sum = s_sum[0] + s_sum[1] + s_sum[2] + s_sum[3];
  sq = s_sq[0] + s_sq[1] + s_sq[2] + s_sq[3];
  float mean = sum * (1.0f / DMODEL);
  float var = sq * (1.0f / DMODEL) - mean * mean;
  float rstd = rsqrtf(var + EPS_LN);
  float4 g = *(const float4*)(gamma + t * 4);
  float4 bb = *(const float4*)(beta + t * 4);
  float4 o4 = {g.x * (x.x - mean) * rstd + bb.x,
               g.y * (x.y - mean) * rstd + bb.y,
               g.z * (x.z - mean) * rstd + bb.z,
               g.w * (x.w - mean) * rstd + bb.w};
  *(float4*)(out + (size_t)r * DMODEL + t * 4) = o4;
}

extern "C" void kernel_launch(void* const* d_in, const int* in_sizes, int n_in,
                              void* d_out, int out_size, void* d_ws, size_t ws_size,
                              hipStream_t stream) {
  const float* h = (const float*)d_in[0];
  const float* Wq = (const float*)d_in[1];
  const float* Wkv = (const float*)d_in[2];
  const float* Wo = (const float*)d_in[3];
  const float* gamma = (const float*)d_in[4];
  const float* beta = (const float*)d_in[5];
  float* out = (float*)d_out;

  float* ws = (float*)d_ws;
  float* proj = ws;                            // [3072][3072] f32 (q|k|v)
  u16* qfeat = (u16*)(proj + 9437184);         // [32][1536][384] bf16
  u16* kfeat = qfeat + 18874368;               // [32][1536][384] bf16
  u16* kfeatT = kfeat + 18874368;              // [32][384][1536] bf16
  u16* vTbf = kfeatT + 18874368;               // [32][64][1536] bf16
  u16* kvstate = vTbf + 3145728;               // [32][24][64][384] bf16
  float* ksumst = (float*)(kvstate + 18874368); // [32][24][384] f32
  u16* attnvec = (u16*)(ksumst + 294912);      // [3072][1024] bf16
  u16* Wo_bf = attnvec + 3145728;              // [1024][1024] bf16
  // bf16 GEMM inputs live in the (not yet written) kvstate slab
  u16* h_bf = kvstate;                         // [3072][1024] bf16
  u16* Wqkv_bf = kvstate + 3145728;            // [3072][1024] bf16 (Wq ; Wkv)
  float* attnout = proj;                       // reuse (proj dead after dpfp)

  hipLaunchKernelGGL(cvt_bf16, dim3(3072), dim3(256), 0, stream, h, h_bf, 786432);
  hipLaunchKernelGGL(cvt_bf16, dim3(1024), dim3(256), 0, stream, Wq, Wqkv_bf, 262144);
  hipLaunchKernelGGL(cvt_bf16, dim3(2048), dim3(256), 0, stream,
                     Wkv, Wqkv_bf + 1048576, 524288);
  hipLaunchKernelGGL(cvt_bf16, dim3(1024), dim3(256), 0, stream, Wo, Wo_bf, 262144);

  // combined projection: [3072 rows] x [3072 outs] x K=1024
  hipLaunchKernelGGL(gemm_bf16_mfma, dim3(24, 24), dim3(256), 0, stream,
                     h_bf, Wqkv_bf, proj, ROWS, 3072, 1024);
  hipLaunchKernelGGL(dpfp_q, dim3(16, 2, 1536), dim3(128), 0, stream,
                     proj, qfeat);
  hipLaunchKernelGGL(dpfp_k64, dim3(24, 32), dim3(256), 0, stream,
                     proj, kfeat, kfeatT, vTbf);
  hipLaunchKernelGGL(chunk_kv_mfma, dim3(24, 32), dim3(256), 0, stream,
                     kfeatT, vTbf, kvstate, ksumst);
  hipLaunchKernelGGL(scan_kernel, dim3(3120), dim3(256), 0, stream,
                     kvstate, ksumst);
  hipLaunchKernelGGL(attn_mfma, dim3(24, 32), dim3(256), 0, stream,
                     qfeat, kfeat, vTbf, kvstate, ksumst, attnvec);
  hipLaunchKernelGGL(gemm64_bf16, dim3(16, 48), dim3(256), 0, stream,
                     attnvec, Wo_bf, attnout, ROWS, 1024, 1024);
  hipLaunchKernelGGL(ln_kernel, dim3(3072), dim3(256), 0, stream,
                     h, attnout, gamma, beta, out);
}

// Round 4
// 168.307 us; speedup vs baseline: 3.6476x; 1.2390x over previous
//
#include <hip/hip_runtime.h>
#include <hip/hip_bf16.h>

#define S_LEN 1536
#define BATCH 2
#define DMODEL 1024
#define NHEAD 16
#define DHEAD 64
#define FDIM 384          // 2*DHEAD*N_ROLL
#define CHUNK 64
#define NCHUNK 24         // S_LEN / CHUNK
#define ROWS (S_LEN*BATCH)
#define SCALE_F 0.125f
#define EPS_D 1e-5f
#define EPS_LN 1e-5f

typedef unsigned short u16;
typedef __attribute__((ext_vector_type(8))) __bf16 bf16x8;
typedef __attribute__((ext_vector_type(8))) unsigned short ushort8;
typedef __attribute__((ext_vector_type(4))) float f32x4;

static __device__ __forceinline__ float bf2f(u16 a) {
  return __uint_as_float(((unsigned)a) << 16);
}
static __device__ __forceinline__ u16 f2bf(float x) {
  unsigned u = __float_as_uint(x);
  unsigned r = (u + 0x7FFFu + ((u >> 16) & 1u)) >> 16;
  return (u16)r;
}
static __device__ __forceinline__ void gload_lds16(const void* g, void* l) {
  __builtin_amdgcn_global_load_lds(
      (const __attribute__((address_space(1))) void*)g,
      (__attribute__((address_space(3))) void*)l, 16, 0, 0);
}
#define MFMA(a, b, c) __builtin_amdgcn_mfma_f32_16x16x32_bf16(a, b, c, 0, 0, 0)

// Fragment-tile layout: buffer [R][C] stored as [R/16][C/32][64][8] u16,
// lane l = kg*16+fr holds (row rT*16+fr, cols cB*32+kg*8 .. +8).
// A wave's fragment load = 64 lanes x 16B contiguous = 1KB stream.

// f32 -> bf16 convert, 4 elems/thread
__global__ __launch_bounds__(256) void cvt_bf16(
    const float* __restrict__ in, u16* __restrict__ out, int n4) {
  int i = blockIdx.x * 256 + threadIdx.x;
  if (i < n4) {
    float4 v = ((const float4*)in)[i];
    ushort4 o = {f2bf(v.x), f2bf(v.y), f2bf(v.z), f2bf(v.w)};
    ((ushort4*)out)[i] = o;
  }
}

// C[M][N] = A[M][K]*B[N][K]^T, bf16 in / f32 out. 128x128 tile, BK=32, 4 waves.
__global__ __launch_bounds__(256) void gemm_bf16_mfma(
    const u16* __restrict__ A, const u16* __restrict__ B,
    float* __restrict__ C, int M, int N, int K) {
  __shared__ u16 As[128 * 32];
  __shared__ u16 Bs[128 * 32];
  const int t = threadIdx.x;
  const int l = t & 63, w = t >> 6;
  const int m0 = blockIdx.y * 128, n0 = blockIdx.x * 128;
  const int wm = (w >> 1) * 64, wn = (w & 1) * 64;

  f32x4 acc[4][4];
#pragma unroll
  for (int i = 0; i < 4; ++i)
#pragma unroll
    for (int j = 0; j < 4; ++j) acc[i][j] = (f32x4)0.f;

  const size_t Kb = (size_t)K * 2;
  const int o_lo = w * 1024 + l * 16;
  const int o_hi = 4096 + w * 1024 + l * 16;
  const int r_lo = o_lo >> 6, kb_lo = o_lo & 63;
  const int r_hi = o_hi >> 6, kb_hi = o_hi & 63;

  const char* Ap0 = (const char*)A + (size_t)(m0 + r_lo) * Kb + kb_lo;
  const char* Ap1 = (const char*)A + (size_t)(m0 + r_hi) * Kb + kb_hi;
  const char* Bp0 = (const char*)B + (size_t)(n0 + r_lo) * Kb + kb_lo;
  const char* Bp1 = (const char*)B + (size_t)(n0 + r_hi) * Kb + kb_hi;
  u16* AsB0 = As + (w * 1024) / 2;
  u16* AsB1 = As + (4096 + w * 1024) / 2;
  u16* BsB0 = Bs + (w * 1024) / 2;
  u16* BsB1 = Bs + (4096 + w * 1024) / 2;

  const int fr = l & 15, ko = (l >> 4) * 8;

  for (int k0 = 0; k0 < K; k0 += 32) {
    __syncthreads();
    gload_lds16(Ap0, AsB0);
    gload_lds16(Ap1, AsB1);
    gload_lds16(Bp0, BsB0);
    gload_lds16(Bp1, BsB1);
    Ap0 += 64; Ap1 += 64; Bp0 += 64; Bp1 += 64;
    __syncthreads();
    bf16x8 a[4], b[4];
#pragma unroll
    for (int m = 0; m < 4; ++m)
      a[m] = *(const bf16x8*)&As[(wm + m * 16 + fr) * 32 + ko];
#pragma unroll
    for (int n = 0; n < 4; ++n)
      b[n] = *(const bf16x8*)&Bs[(wn + n * 16 + fr) * 32 + ko];
#pragma unroll
    for (int m = 0; m < 4; ++m)
#pragma unroll
      for (int n = 0; n < 4; ++n)
        acc[m][n] = MFMA(a[m], b[n], acc[m][n]);
  }

  const int cr = (l >> 4) * 4, ccol = l & 15;
#pragma unroll
  for (int m = 0; m < 4; ++m)
#pragma unroll
    for (int n = 0; n < 4; ++n)
#pragma unroll
      for (int j = 0; j < 4; ++j)
        C[(size_t)(m0 + wm + m * 16 + cr + j) * N + (n0 + wn + n * 16 + ccol)] =
            acc[m][n][j];
}

// 64x64 tile, BK=32, 4 waves each 16(m)x64(n). For skinny GEMMs (more blocks).
__global__ __launch_bounds__(256) void gemm64_bf16(
    const u16* __restrict__ A, const u16* __restrict__ B,
    float* __restrict__ C, int M, int N, int K) {
  __shared__ u16 As[64 * 32];
  __shared__ u16 Bs[64 * 32];
  const int t = threadIdx.x;
  const int l = t & 63, w = t >> 6;
  const int m0 = blockIdx.y * 64, n0 = blockIdx.x * 64;
  const int fr = l & 15, kg = l >> 4;
  const size_t Kb = (size_t)K * 2;
  const int o = t * 16, r = o >> 6, kb = o & 63;
  const char* Ap = (const char*)A + (size_t)(m0 + r) * Kb + kb;
  const char* Bp = (const char*)B + (size_t)(n0 + r) * Kb + kb;
  u16* AsB = As + (w * 1024) / 2;
  u16* BsB = Bs + (w * 1024) / 2;
  f32x4 acc[4];
#pragma unroll
  for (int i = 0; i < 4; ++i) acc[i] = (f32x4)0.f;
  for (int k0 = 0; k0 < K; k0 += 32) {
    __syncthreads();
    gload_lds16(Ap, AsB);
    gload_lds16(Bp, BsB);
    Ap += 64; Bp += 64;
    __syncthreads();
    bf16x8 a = *(const bf16x8*)&As[(16 * w + fr) * 32 + kg * 8];
#pragma unroll
    for (int nt = 0; nt < 4; ++nt) {
      bf16x8 b = *(const bf16x8*)&Bs[(16 * nt + fr) * 32 + kg * 8];
      acc[nt] = MFMA(a, b, acc[nt]);
    }
  }
#pragma unroll
  for (int nt = 0; nt < 4; ++nt)
#pragma unroll
    for (int reg = 0; reg < 4; ++reg)
      C[(size_t)(m0 + 16 * w + 4 * kg + reg) * N + (n0 + 16 * nt + fr)] =
          acc[nt][reg];
}

// DPFP for q: per (c,bn) block over 64 s-rows. Writes qf_t fragment tiles.
__global__ __launch_bounds__(256) void dpfp_q64(
    const float* __restrict__ proj, u16* __restrict__ qft) {
  const int c = blockIdx.x, bn = blockIdx.y;
  const int b = bn >> 4, n = bn & 15;
  const int s0 = c * CHUNK;
  const int t = threadIdx.x;
  __shared__ float y[64][129];
  const int j = t >> 2, dq = (t & 3) << 4;
  const float* qp = proj + (size_t)((s0 + j) * BATCH + b) * 3072 + n * DHEAD + dq;
#pragma unroll
  for (int u = 0; u < 4; ++u) {
    float4 xv = *(const float4*)(qp + 4 * u);
    int d = dq + 4 * u;
    y[j][d + 0] = fmaxf(xv.x, 0.f); y[j][64 + d + 0] = fmaxf(-xv.x, 0.f);
    y[j][d + 1] = fmaxf(xv.y, 0.f); y[j][64 + d + 1] = fmaxf(-xv.y, 0.f);
    y[j][d + 2] = fmaxf(xv.z, 0.f); y[j][64 + d + 2] = fmaxf(-xv.z, 0.f);
    y[j][d + 3] = fmaxf(xv.w, 0.f); y[j][64 + d + 3] = fmaxf(-xv.w, 0.f);
  }
  __syncthreads();
  u16* base = qft + (size_t)bn * 589824;  // [96 rT][12 cB][512]
  const int fr = t & 15, kg = (t >> 4) & 3, l = t & 63;
#pragma unroll 2
  for (int it = 0; it < 12; ++it) {
    int tile = it * 4 + (t >> 6);          // 0..47: rTloc*12 + cB
    int rT = tile / 12, cB = tile % 12;
    int sl = rT * 16 + fr;
    ushort8 o;
#pragma unroll
    for (int e = 0; e < 8; ++e) {
      int f = cB * 32 + kg * 8 + e, m = f & 127, sh = (f >> 7) + 1;
      o[e] = f2bf(y[sl][m] * y[sl][(m - sh) & 127]);
    }
    *(ushort8*)(base + ((size_t)(4 * c + rT) * 12 + cB) * 512 + l * 8) = o;
  }
}

// DPFP for k (+v): per (c,bn) block. Writes kf_t [S/16][F/32] tiles,
// kfT_t [F/16][S/32] tiles, vT_t [64/16][S/32] tiles.
__global__ __launch_bounds__(256) void dpfp_k64(
    const float* __restrict__ proj, u16* __restrict__ kft,
    u16* __restrict__ kfTt, u16* __restrict__ vTt) {
  const int c = blockIdx.x, bn = blockIdx.y;
  const int b = bn >> 4, n = bn & 15;
  const int s0 = c * CHUNK;
  const int t = threadIdx.x;
  __shared__ float y[64][129];
  __shared__ float vs[64][65];
  const int j = t >> 2, dq = (t & 3) << 4;
  const float* kp = proj + (size_t)((s0 + j) * BATCH + b) * 3072 + n * DHEAD + dq;
#pragma unroll
  for (int u = 0; u < 4; ++u) {
    float4 xv = *(const float4*)(kp + 1024 + 4 * u);   // k cols
    float4 vv = *(const float4*)(kp + 2048 + 4 * u);   // v cols
    int d = dq + 4 * u;
    y[j][d + 0] = fmaxf(xv.x, 0.f); y[j][64 + d + 0] = fmaxf(-xv.x, 0.f);
    y[j][d + 1] = fmaxf(xv.y, 0.f); y[j][64 + d + 1] = fmaxf(-xv.y, 0.f);
    y[j][d + 2] = fmaxf(xv.z, 0.f); y[j][64 + d + 2] = fmaxf(-xv.z, 0.f);
    y[j][d + 3] = fmaxf(xv.w, 0.f); y[j][64 + d + 3] = fmaxf(-xv.w, 0.f);
    vs[j][d + 0] = vv.x; vs[j][d + 1] = vv.y;
    vs[j][d + 2] = vv.z; vs[j][d + 3] = vv.w;
  }
  __syncthreads();
  const int fr = t & 15, kg = (t >> 4) & 3, l = t & 63;
  // kf_t tiles (rows s, cols f)
  {
    u16* base = kft + (size_t)bn * 589824;
#pragma unroll 2
    for (int it = 0; it < 12; ++it) {
      int tile = it * 4 + (t >> 6);
      int rT = tile / 12, cB = tile % 12;
      int sl = rT * 16 + fr;
      ushort8 o;
#pragma unroll
      for (int e = 0; e < 8; ++e) {
        int f = cB * 32 + kg * 8 + e, m = f & 127, sh = (f >> 7) + 1;
        o[e] = f2bf(y[sl][m] * y[sl][(m - sh) & 127]);
      }
      *(ushort8*)(base + ((size_t)(4 * c + rT) * 12 + cB) * 512 + l * 8) = o;
    }
  }
  // kfT_t tiles (rows f: 24 rT, cols s: this chunk covers cB = 2c, 2c+1)
  {
    u16* base = kfTt + (size_t)bn * 589824;
#pragma unroll 2
    for (int it = 0; it < 12; ++it) {
      int tile = it * 4 + (t >> 6);          // 0..47: rT*2 + cHalf
      int rT = tile >> 1, cHalf = tile & 1;
      int f = rT * 16 + fr, m = f & 127, sh = (f >> 7) + 1;
      int sb = cHalf * 32 + kg * 8;
      ushort8 o;
#pragma unroll
      for (int e = 0; e < 8; ++e)
        o[e] = f2bf(y[sb + e][m] * y[sb + e][(m - sh) & 127]);
      *(ushort8*)(base + ((size_t)rT * 48 + 2 * c + cHalf) * 512 + l * 8) = o;
    }
  }
  // vT_t tiles (rows d: 4 rT, cols s)
  {
    u16* base = vTt + (size_t)bn * 98304;
#pragma unroll
    for (int it = 0; it < 2; ++it) {
      int tile = it * 4 + (t >> 6);          // 0..7: rT*2 + cHalf
      int rT = tile >> 1, cHalf = tile & 1;
      int d = rT * 16 + fr;
      int sb = cHalf * 32 + kg * 8;
      ushort8 o;
#pragma unroll
      for (int e = 0; e < 8; ++e) o[e] = f2bf(vs[sb + e][d]);
      *(ushort8*)(base + ((size_t)rT * 48 + 2 * c + cHalf) * 512 + l * 8) = o;
    }
  }
}

// Per-chunk KV sums via MFMA: KV_c[d][f] (bf16, linear [d][f]) + ksum_c[f] f32.
__global__ __launch_bounds__(256) void chunk_kv_mfma(
    const u16* __restrict__ kfTt, const u16* __restrict__ vTt,
    u16* __restrict__ kvlin, float* __restrict__ ksumst) {
  const int c = blockIdx.x, bn = blockIdx.y;
  const int t = threadIdx.x, l = t & 63, w = t >> 6;
  const int fr = l & 15, kg = l >> 4;
  const u16* vt_base = vTt + (size_t)bn * 98304;
  const u16* kt_base = kfTt + (size_t)bn * 589824;

  f32x4 acc[4][6];
#pragma unroll
  for (int m = 0; m < 4; ++m)
#pragma unroll
    for (int nt = 0; nt < 6; ++nt) acc[m][nt] = (f32x4)0.f;
  float ks[6] = {0.f, 0.f, 0.f, 0.f, 0.f, 0.f};

#pragma unroll
  for (int ksi = 0; ksi < 2; ++ksi) {
    bf16x8 a[4];
#pragma unroll
    for (int m = 0; m < 4; ++m)
      a[m] = *(const bf16x8*)(vt_base + ((size_t)m * 48 + 2 * c + ksi) * 512 + l * 8);
#pragma unroll
    for (int nt = 0; nt < 6; ++nt) {
      const u16* bp = kt_base + ((size_t)(6 * w + nt) * 48 + 2 * c + ksi) * 512 + l * 8;
      bf16x8 bfrag = *(const bf16x8*)bp;
      ushort8 raw = *(const ushort8*)bp;
#pragma unroll
      for (int e = 0; e < 8; ++e) ks[nt] += bf2f(raw[e]);
#pragma unroll
      for (int m = 0; m < 4; ++m) acc[m][nt] = MFMA(a[m], bfrag, acc[m][nt]);
    }
  }
#pragma unroll
  for (int nt = 0; nt < 6; ++nt) {
    float x = ks[nt];
    x += __shfl_xor(x, 16);
    x += __shfl_xor(x, 32);
    ks[nt] = x;
  }
  if (l < 16) {
    float* kso = ksumst + (size_t)(bn * NCHUNK + c) * FDIM + 96 * w;
#pragma unroll
    for (int nt = 0; nt < 6; ++nt) kso[16 * nt + l] = ks[nt];
  }
  u16* outp = kvlin + (size_t)(bn * NCHUNK + c) * (64 * FDIM);
#pragma unroll
  for (int m = 0; m < 4; ++m)
#pragma unroll
    for (int nt = 0; nt < 6; ++nt)
#pragma unroll
      for (int reg = 0; reg < 4; ++reg) {
        int d = 16 * m + 4 * kg + reg, f = 96 * w + 16 * nt + fr;
        outp[(size_t)d * FDIM + f] = f2bf(acc[m][nt][reg]);
      }
}

// Exclusive chunk-prefix: kvlin -> kvswz fragment tiles [bn][c][4 dT][12 cB][512];
// plus ksumst prefix in place.
__global__ __launch_bounds__(256) void scan_relayout(
    const u16* __restrict__ kvlin, float* __restrict__ ksumst,
    u16* __restrict__ kvswz) {
  const int bid = blockIdx.x;
  if (bid < 1536) {
    const int bn = bid / 48, rem = bid % 48, dT = rem / 12, cB = rem % 12;
    const int t = threadIdx.x;
    const int p = t * 2, l = p >> 3, e0 = p & 7;
    const int fr = l & 15, kg = l >> 4;
    const int d = dT * 16 + fr, f = cB * 32 + kg * 8 + e0;
    const u16* src = kvlin + (size_t)bn * (NCHUNK * 24576) + d * FDIM + f;
    float a0 = 0.f, a1 = 0.f;
    for (int c = 0; c < NCHUNK; ++c) {
      const u16* s2 = src + (size_t)c * 24576;
      float x0 = bf2f(s2[0]), x1 = bf2f(s2[1]);
      u16* dp = kvswz + (((size_t)(bn * NCHUNK + c) * 4 + dT) * 12 + cB) * 512 + l * 8 + e0;
      dp[0] = f2bf(a0); dp[1] = f2bf(a1);
      a0 += x0; a1 += x1;
    }
  } else {
    int gid = (bid - 1536) * 256 + threadIdx.x;   // 32*384 chains
    int bn = gid / FDIM, f = gid % FDIM;
    float* base = ksumst + (size_t)bn * NCHUNK * FDIM + f;
    float a = 0.f;
    for (int c = 0; c < NCHUNK; ++c) {
      float x = base[(size_t)c * FDIM];
      base[(size_t)c * FDIM] = a;
      a += x;
    }
  }
}

// Fused attention, MFMA, fragment-tiled operands. Grid (c, bn), 4 waves.
// acc[0..3]=intra scores, acc[4..7]=inter output, acc[8]=den (ksum B-tile).
__global__ __launch_bounds__(256) void attn_mfma(
    const u16* __restrict__ qft, const u16* __restrict__ kft,
    const u16* __restrict__ vTt, const u16* __restrict__ kvswz,
    const float* __restrict__ kspre, u16* __restrict__ attnvec) {
  const int c = blockIdx.x, bn = blockIdx.y;
  const int b = bn >> 4, n = bn & 15;
  const int s0 = c * CHUNK;
  const int t = threadIdx.x, l = t & 63, w = t >> 6;
  const int fr = l & 15, kg = l >> 4;

  const u16* qbase = qft + (size_t)bn * 589824;
  const u16* kbase = kft + (size_t)bn * 589824;
  const u16* vbase = vTt + (size_t)bn * 98304;
  const u16* kvbase = kvswz + (size_t)(bn * NCHUNK + c) * 24576;
  const float* ksp = kspre + (size_t)(bn * NCHUNK + c) * FDIM;

  __shared__ u16 Sb[64][70];

  f32x4 acc[9];
#pragma unroll
  for (int i = 0; i < 9; ++i) acc[i] = (f32x4)0.f;

#pragma unroll 3
  for (int cB = 0; cB < 12; ++cB) {
    bf16x8 a = *(const bf16x8*)(qbase + ((size_t)(4 * c + w) * 12 + cB) * 512 + l * 8);
#pragma unroll
    for (int nt = 0; nt < 4; ++nt) {
      bf16x8 bfrag = *(const bf16x8*)(kbase + ((size_t)(4 * c + nt) * 12 + cB) * 512 + l * 8);
      acc[nt] = MFMA(a, bfrag, acc[nt]);
    }
#pragma unroll
    for (int nt = 0; nt < 4; ++nt) {
      bf16x8 bfrag = *(const bf16x8*)(kvbase + ((size_t)nt * 12 + cB) * 512 + l * 8);
      acc[4 + nt] = MFMA(a, bfrag, acc[4 + nt]);
    }
    // den B-tile: row fr==0 holds prefixed ksum, rest zero
    ushort8 bd = {0, 0, 0, 0, 0, 0, 0, 0};
    if (fr == 0) {
#pragma unroll
      for (int e = 0; e < 8; ++e) bd[e] = f2bf(ksp[cB * 32 + kg * 8 + e]);
    }
    union { ushort8 u; bf16x8 v; } cu;
    cu.u = bd;
    acc[8] = MFMA(a, cu.v, acc[8]);
  }

  // mask (j>i -> 0) + intra rowsum (butterfly over fr lanes) + S -> LDS bf16
  float rsum[4];
#pragma unroll
  for (int reg = 0; reg < 4; ++reg) {
    int i = 16 * w + 4 * kg + reg;
    float r = 0.f;
#pragma unroll
    for (int nt = 0; nt < 4; ++nt) {
      int jj = 16 * nt + fr;
      float sval = (jj <= i) ? acc[nt][reg] : 0.f;
      acc[nt][reg] = sval;
      r += sval;
    }
    r += __shfl_xor(r, 1); r += __shfl_xor(r, 2);
    r += __shfl_xor(r, 4); r += __shfl_xor(r, 8);
    rsum[reg] = r;
  }
#pragma unroll
  for (int nt = 0; nt < 4; ++nt)
#pragma unroll
    for (int reg = 0; reg < 4; ++reg)
      Sb[16 * w + 4 * kg + reg][16 * nt + fr] = f2bf(acc[nt][reg]);

  __syncthreads();

  // PV: acc[4..7] += S * vT
#pragma unroll
  for (int ksi = 0; ksi < 2; ++ksi) {
    const int ko = ksi * 32 + kg * 8;
    bf16x8 a = *(const bf16x8*)&Sb[16 * w + fr][ko];
#pragma unroll
    for (int nt = 0; nt < 4; ++nt) {
      bf16x8 bfrag = *(const bf16x8*)(vbase + ((size_t)nt * 48 + 2 * c + ksi) * 512 + l * 8);
      acc[4 + nt] = MFMA(a, bfrag, acc[4 + nt]);
    }
  }

  // normalize + store; den for row i held by lane (kg, fr=0) in acc[8]
#pragma unroll
  for (int reg = 0; reg < 4; ++reg) {
    int i = 16 * w + 4 * kg + reg;
    float dinter = __shfl(acc[8][reg], l & 48);
    float den = rsum[reg] + dinter;
    float sc = SCALE_F / (SCALE_F * den + EPS_D);
    int rowg = (s0 + i) * BATCH + b;
    u16* orow = attnvec + (size_t)rowg * DMODEL + n * DHEAD;
#pragma unroll
    for (int nt = 0; nt < 4; ++nt)
      orow[16 * nt + fr] = f2bf(acc[4 + nt][reg] * sc);
  }
}

// out = LN(h + attn_out) * gamma + beta
__global__ __launch_bounds__(256) void ln_kernel(
    const float* __restrict__ h, const float* __restrict__ ao,
    const float* __restrict__ gamma, const float* __restrict__ beta,
    float* __restrict__ out) {
  const int r = blockIdx.x, t = threadIdx.x;
  const float* hr = h + (size_t)r * DMODEL;
  const float* ar = ao + (size_t)r * DMODEL;
  float4 xh = *(const float4*)(hr + t * 4);
  float4 xa = *(const float4*)(ar + t * 4);
  float4 x = {xh.x + xa.x, xh.y + xa.y, xh.z + xa.z, xh.w + xa.w};
  float sum = x.x + x.y + x.z + x.w;
  float sq = x.x * x.x + x.y * x.y + x.z * x.z + x.w * x.w;
#pragma unroll
  for (int o = 32; o >= 1; o >>= 1) {
    sum += __shfl_xor(sum, o);
    sq += __shfl_xor(sq, o);
  }
  __shared__ float s_sum[4], s_sq[4];
  int w = t >> 6;
  if ((t & 63) == 0) { s_sum[w] = sum; s_sq[w] = sq; }
  __syncthreads();
  sum = s_sum[0] + s_sum[1] + s_sum[2] + s_sum[3];
  sq = s_sq[0] + s_sq[1] + s_sq[2] + s_sq[3];
  float mean = sum * (1.0f / DMODEL);
  float var = sq * (1.0f / DMODEL) - mean * mean;
  float rstd = rsqrtf(var + EPS_LN);
  float4 g = *(const float4*)(gamma + t * 4);
  float4 bb = *(const float4*)(beta + t * 4);
  float4 o4 = {g.x * (x.x - mean) * rstd + bb.x,
               g.y * (x.y - mean) * rstd + bb.y,
               g.z * (x.z - mean) * rstd + bb.z,
               g.w * (x.w - mean) * rstd + bb.w};
  *(float4*)(out + (size_t)r * DMODEL + t * 4) = o4;
}

extern "C" void kernel_launch(void* const* d_in, const int* in_sizes, int n_in,
                              void* d_out, int out_size, void* d_ws, size_t ws_size,
                              hipStream_t stream) {
  const float* h = (const float*)d_in[0];
  const float* Wq = (const float*)d_in[1];
  const float* Wkv = (const float*)d_in[2];
  const float* Wo = (const float*)d_in[3];
  const float* gamma = (const float*)d_in[4];
  const float* beta = (const float*)d_in[5];
  float* out = (float*)d_out;

  float* ws = (float*)d_ws;
  // slabs (f32-elem offsets); reuse plan keeps peak ~198MB
  float* proj = ws;                             // [3072][3072] f32; later kvswz
  u16* qft = (u16*)(proj + 9437184);            // [32]*589824 u16 frag tiles
  u16* kft = qft + 18874368;                    // same; later attnout (f32) slab
  u16* kfTt = kft + 18874368;                   // [32]*589824 u16
  u16* vTt = kfTt + 18874368;                   // [32]*98304 u16
  u16* kvlin = vTt + 3145728;                   // [32][24][64][384] bf16
  float* ksumst = (float*)(kvlin + 18874368);   // [32][24][384] f32
  u16* Wo_bf = (u16*)(ksumst + 294912);         // [1024][1024] bf16
  // overlays:
  u16* h_bf = kvlin;                            // [3072][1024] bf16 (pre chunk_kv)
  u16* Wqkv_bf = kvlin + 3145728;               // [3072][1024] bf16 (pre chunk_kv)
  u16* kvswz = (u16*)proj;                      // [32][24][4][12][512] bf16 (post dpfp)
  u16* attnvec = kvlin;                         // [3072][1024] bf16 (post scan)
  float* attnout = (float*)kft;                 // [3072][1024] f32 (post attn)

  hipLaunchKernelGGL(cvt_bf16, dim3(3072), dim3(256), 0, stream, h, h_bf, 786432);
  hipLaunchKernelGGL(cvt_bf16, dim3(1024), dim3(256), 0, stream, Wq, Wqkv_bf, 262144);
  hipLaunchKernelGGL(cvt_bf16, dim3(2048), dim3(256), 0, stream,
                     Wkv, Wqkv_bf + 1048576, 524288);
  hipLaunchKernelGGL(cvt_bf16, dim3(1024), dim3(256), 0, stream, Wo, Wo_bf, 262144);

  hipLaunchKernelGGL(gemm_bf16_mfma, dim3(24, 24), dim3(256), 0, stream,
                     h_bf, Wqkv_bf, proj, ROWS, 3072, 1024);
  hipLaunchKernelGGL(dpfp_q64, dim3(24, 32), dim3(256), 0, stream, proj, qft);
  hipLaunchKernelGGL(dpfp_k64, dim3(24, 32), dim3(256), 0, stream,
                     proj, kft, kfTt, vTt);
  hipLaunchKernelGGL(chunk_kv_mfma, dim3(24, 32), dim3(256), 0, stream,
                     kfTt, vTt, kvlin, ksumst);
  hipLaunchKernelGGL(scan_relayout, dim3(1584), dim3(256), 0, stream,
                     kvlin, ksumst, kvswz);
  hipLaunchKernelGGL(attn_mfma, dim3(24, 32), dim3(256), 0, stream,
                     qft, kft, vTt, kvswz, ksumst, attnvec);
  hipLaunchKernelGGL(gemm64_bf16, dim3(16, 48), dim3(256), 0, stream,
                     attnvec, Wo_bf, attnout, ROWS, 1024, 1024);
  hipLaunchKernelGGL(ln_kernel, dim3(3072), dim3(256), 0, stream,
                     h, attnout, gamma, beta, out);
}